// Round 2
// baseline (1299.306 us; speedup 1.0000x reference)
//
#include <hip/hip_runtime.h>
#include <hip/hip_bf16.h>

#define N_NODES 50000
#define N_EDGES 800000
#define IN_FEAT 100
#define OUT_FEAT 100
#define NUM_RELS 200
#define NUM_HEADS 3

#define KP 128          // padded K (100 -> 128)
#define NPH 112         // per-head padded N (100 -> 112 = 7*16)
#define NP  336         // 3 * 112
#define MB  128         // edges per block
#define NT_ALL 21       // NP/16
#define NT_O 7          // NPH/16
#define MSG_STRIDE 112  // ushorts per msg row (224 B)

// ---- workspace layout (bytes) ----
#define WS_B       0u
#define WS_CNT     86272u
#define WS_OFFS    286976u
#define WS_CURSOR  487680u
#define WS_BSUM    688384u
#define WS_PERM    688640u
#define WS_MSG     3888640u
#define WS_NEEDED  183088640u
#define NNODES_PAD 50176    // 49*1024

typedef __attribute__((ext_vector_type(8))) short short8;
typedef __attribute__((ext_vector_type(4))) float f32x4;

__device__ __forceinline__ unsigned short f2bf(float f) {
    unsigned u = __builtin_bit_cast(unsigned, f);
    unsigned r = u + 0x7FFFu + ((u >> 16) & 1u);
    return (unsigned short)(r >> 16);
}
__device__ __forceinline__ float bf2f(unsigned hs) {
    return __builtin_bit_cast(float, hs << 16);
}

// ---------------------------------------------------------------------------
// Prep: B = fc_w^T (bf16), layout [n=336][k-storage=128], UNswizzled (global
// image, read directly by edge kernel fragments; L2-resident, 86 KB).
// k-storage granule g (=kt*4+g4), elem j2 in [0,8): k = kt*32+(j2>>2)*16+g4*4+(j2&3)
// ---------------------------------------------------------------------------
__global__ __launch_bounds__(256) void build_B(const float* __restrict__ fc_w,
                                               unsigned short* __restrict__ Bws) {
    int idx = blockIdx.x * 256 + threadIdx.x;     // granule id: n*16 + g
    if (idx >= NP * 16) return;
    int n = idx >> 4, g = idx & 15;
    int head = n / NPH, o = n - head * NPH;
    int kt = g >> 2, g4 = g & 3;
    unsigned p[4];
#pragma unroll
    for (int half = 0; half < 2; ++half) {
#pragma unroll
        for (int jp = 0; jp < 2; ++jp) {
            int k_lo = kt * 32 + half * 16 + g4 * 4 + jp * 2;
            int k_hi = k_lo + 1;
            float vlo = (k_lo < IN_FEAT && o < OUT_FEAT)
                      ? fc_w[k_lo * (OUT_FEAT * NUM_HEADS) + head * OUT_FEAT + o] : 0.f;
            float vhi = (k_hi < IN_FEAT && o < OUT_FEAT)
                      ? fc_w[k_hi * (OUT_FEAT * NUM_HEADS) + head * OUT_FEAT + o] : 0.f;
            p[half * 2 + jp] = (unsigned)f2bf(vlo) | ((unsigned)f2bf(vhi) << 16);
        }
    }
    reinterpret_cast<int4*>(Bws)[idx] = make_int4((int)p[0], (int)p[1], (int)p[2], (int)p[3]);
}

// ---------------------------------------------------------------------------
// Self-loop init: out = h @ loop_w
// ---------------------------------------------------------------------------
__global__ __launch_bounds__(256) void loop_kernel(const float* __restrict__ h,
                                                   const float* __restrict__ loop_w,
                                                   float* __restrict__ out) {
    __shared__ float ws[IN_FEAT * OUT_FEAT];
    __shared__ float hs[2][IN_FEAT];
    for (int i = threadIdx.x; i < IN_FEAT * OUT_FEAT; i += 256) ws[i] = loop_w[i];
    int row0 = blockIdx.x * 16;
    int o  = threadIdx.x & 127;
    int rr = threadIdx.x >> 7;
    __syncthreads();
    for (int r = 0; r < 16; r += 2) {
        if (threadIdx.x < 2 * IN_FEAT) {
            int which = threadIdx.x / IN_FEAT, k = threadIdx.x - which * IN_FEAT;
            hs[which][k] = h[(row0 + r + which) * IN_FEAT + k];
        }
        __syncthreads();
        if (o < OUT_FEAT) {
            float acc = 0.f;
#pragma unroll 4
            for (int k = 0; k < IN_FEAT; ++k)
                acc = fmaf(hs[rr][k], ws[k * OUT_FEAT + o], acc);
            out[(row0 + r + rr) * OUT_FEAT + o] = acc;
        }
        __syncthreads();
    }
}

// ---------------------------------------------------------------------------
// CSR construction: histogram -> scan -> scatter
// ---------------------------------------------------------------------------
__global__ __launch_bounds__(512) void hist_kernel(const int* __restrict__ dst,
                                                   int* __restrict__ cnt) {
    int e = blockIdx.x * 512 + threadIdx.x;
    if (e < N_EDGES) atomicAdd(&cnt[dst[e]], 1);
}

__global__ __launch_bounds__(1024) void scan1(const int* __restrict__ cnt,
                                              int* __restrict__ offs,
                                              int* __restrict__ bsum) {
    __shared__ int s[1024];
    int i = blockIdx.x * 1024 + threadIdx.x;
    int v = (i < N_NODES) ? cnt[i] : 0;
    s[threadIdx.x] = v;
    __syncthreads();
    for (int d = 1; d < 1024; d <<= 1) {
        int t = (threadIdx.x >= d) ? s[threadIdx.x - d] : 0;
        __syncthreads();
        s[threadIdx.x] += t;
        __syncthreads();
    }
    offs[i] = s[threadIdx.x] - v;                    // exclusive within block
    if (threadIdx.x == 1023) bsum[blockIdx.x] = s[1023];
}

__global__ __launch_bounds__(64) void scan2(int* __restrict__ bsum) {
    __shared__ int s[64];
    int v = (threadIdx.x < 49) ? bsum[threadIdx.x] : 0;
    s[threadIdx.x] = v;
    __syncthreads();
    for (int d = 1; d < 64; d <<= 1) {
        int t = (threadIdx.x >= d) ? s[threadIdx.x - d] : 0;
        __syncthreads();
        s[threadIdx.x] += t;
        __syncthreads();
    }
    bsum[threadIdx.x] = s[threadIdx.x] - v;          // exclusive
}

__global__ __launch_bounds__(1024) void scan3(int* __restrict__ offs,
                                              const int* __restrict__ bsum,
                                              int* __restrict__ cursor) {
    int i = blockIdx.x * 1024 + threadIdx.x;
    int v = offs[i] + bsum[blockIdx.x];
    offs[i] = v;
    cursor[i] = v;
}

__global__ __launch_bounds__(512) void scatter_kernel(const int* __restrict__ dst,
                                                      int* __restrict__ cursor,
                                                      int* __restrict__ perm) {
    int e = blockIdx.x * 512 + threadIdx.x;
    if (e < N_EDGES) {
        int p = atomicAdd(&cursor[dst[e]], 1);
        perm[p] = e;
    }
}

// ---------------------------------------------------------------------------
// Fused edge kernel: fc GEMM (bf16 MFMA) + attention fuse + msg + norm.
// ATOMIC=true: scatter-add to out (fallback). ATOMIC=false: coalesced bf16
// msg rows to workspace (stride 112 ushorts).
// ---------------------------------------------------------------------------
template<bool ATOMIC>
__global__ __launch_bounds__(512, 4) void edge_kernel(
        const float* __restrict__ h, const float* __restrict__ efeat,
        const float* __restrict__ norm, const float* __restrict__ weight,
        const float* __restrict__ attn, const int* __restrict__ rel,
        const int* __restrict__ src, const int* __restrict__ dst,
        const unsigned short* __restrict__ Bimg, float* __restrict__ out,
        unsigned short* __restrict__ msg) {

    __shared__ unsigned short Alds[MB * KP];   // 32768 B, swizzled; reused as msg staging
    __shared__ int   m_rel[MB];
    __shared__ int   m_src[MB];
    __shared__ int   m_dst[MB];
    __shared__ float m_nrm[MB];

    const int tid = threadIdx.x;
    const int ebase = blockIdx.x * MB;

    if (tid < MB) {
        int ei = ebase + tid;
        int rl = rel[ei]; int sr = src[ei]; int d = dst[ei];
        m_rel[tid] = rl; m_src[tid] = sr; m_dst[tid] = d; m_nrm[tid] = norm[d];
    }
    // ---- stage A: e rows f32 -> bf16, XOR-swizzled ----
    for (int gi = tid; gi < MB * 16; gi += 512) {
        int row = gi >> 4, g = gi & 15;
        int kt = g >> 2, g4 = g & 3;
        const float* erow = efeat + (size_t)(ebase + row) * IN_FEAT;
        int k0 = kt * 32 + g4 * 4;
        int k1 = k0 + 16;
        float4 va = (k0 + 4 <= IN_FEAT) ? *reinterpret_cast<const float4*>(erow + k0)
                                        : make_float4(0.f, 0.f, 0.f, 0.f);
        float4 vb = (k1 + 4 <= IN_FEAT) ? *reinterpret_cast<const float4*>(erow + k1)
                                        : make_float4(0.f, 0.f, 0.f, 0.f);
        unsigned p0 = (unsigned)f2bf(va.x) | ((unsigned)f2bf(va.y) << 16);
        unsigned p1 = (unsigned)f2bf(va.z) | ((unsigned)f2bf(va.w) << 16);
        unsigned p2 = (unsigned)f2bf(vb.x) | ((unsigned)f2bf(vb.y) << 16);
        unsigned p3 = (unsigned)f2bf(vb.z) | ((unsigned)f2bf(vb.w) << 16);
        unsigned off = ((unsigned)(row * (KP * 2) + g * 16)) ^ (((unsigned)(row & 7)) << 4);
        *reinterpret_cast<int4*>(reinterpret_cast<char*>(Alds) + off) =
            make_int4((int)p0, (int)p1, (int)p2, (int)p3);
    }
    __syncthreads();

    // ---- MFMA main loop (A from LDS, B fragments straight from L2-resident global) ----
    const int wave = tid >> 6;
    const int lane = tid & 63;
    const int lrow = lane & 15;
    const int lk   = lane >> 4;

    f32x4 acc[NT_ALL];
#pragma unroll
    for (int i = 0; i < NT_ALL; ++i) acc[i] = (f32x4){0.f, 0.f, 0.f, 0.f};

    const int arow = wave * 16 + lrow;
    const unsigned aswz = ((unsigned)(arow & 7)) << 4;

#pragma unroll
    for (int kt = 0; kt < 4; ++kt) {
        unsigned aoff = ((unsigned)(arow * (KP * 2) + kt * 64 + lk * 16)) ^ aswz;
        short8 afrag = *reinterpret_cast<const short8*>(
            reinterpret_cast<const char*>(Alds) + aoff);
#pragma unroll
        for (int nt = 0; nt < NT_ALL; ++nt) {
            int n = nt * 16 + lrow;
            short8 bfrag = *reinterpret_cast<const short8*>(
                Bimg + (size_t)(n * KP + kt * 32 + lk * 8));
            acc[nt] = __builtin_amdgcn_mfma_f32_16x16x32_bf16(afrag, bfrag, acc[nt], 0, 0, 0);
        }
    }

    if (!ATOMIC) __syncthreads();   // all waves done reading Alds before reuse

    // ---- epilogue: msg + attention fuse + norm scale ----
    // C/D layout: col(o) = lane&15, row(edge) = (lane>>4)*4 + reg
#pragma unroll
    for (int nt = 0; nt < NT_O; ++nt) {
        int o = nt * 16 + lrow;
        if (o < OUT_FEAT) {
#pragma unroll
            for (int r = 0; r < 4; ++r) {
                int el = wave * 16 + lk * 4 + r;
                int rl = m_rel[el];
                int sr = m_src[el];
                float nm = m_nrm[el];
                float mg = h[sr * IN_FEAT + o] * weight[rl * OUT_FEAT + o];
                float feat = 0.f;
#pragma unroll
                for (int hh = 0; hh < NUM_HEADS; ++hh) {
                    float v = acc[nt + NT_O * hh][r] *
                              attn[rl * (NUM_HEADS * OUT_FEAT) + hh * OUT_FEAT + o];
                    feat += (v > 0.f) ? v : 0.2f * v;
                }
                float val = (mg + feat) * nm;
                if (ATOMIC) {
                    atomicAdd(&out[m_dst[el] * OUT_FEAT + o], val);
                } else {
                    Alds[el * MSG_STRIDE + o] = f2bf(val);
                }
            }
        }
    }

    if (!ATOMIC) {
        __syncthreads();
        // coalesced writeout: 128 rows x 112 ushorts = 1792 int4
        int4* gp = reinterpret_cast<int4*>(msg + (size_t)ebase * MSG_STRIDE);
        const int4* sp = reinterpret_cast<const int4*>(Alds);
        for (int i = tid; i < MB * MSG_STRIDE / 8; i += 512) gp[i] = sp[i];
    }
}

// ---------------------------------------------------------------------------
// Gather: per node, sum its edges' msg rows (CSR), out += sum
// ---------------------------------------------------------------------------
__global__ __launch_bounds__(256) void gather_kernel(
        const unsigned short* __restrict__ msg, const int* __restrict__ offs,
        const int* __restrict__ cnt, const int* __restrict__ perm,
        float* __restrict__ out) {
    int wv = threadIdx.x >> 6, lane = threadIdx.x & 63;
    int n = blockIdx.x * 4 + wv;
    if (n >= N_NODES) return;
    int start = offs[n], deg = cnt[n];
    float ax = 0.f, ay = 0.f;
    const unsigned* mp = reinterpret_cast<const unsigned*>(msg);

    for (int base = 0; base < deg; base += 64) {
        int rem = deg - base; if (rem > 64) rem = 64;
        int eidv = (base + lane < deg) ? perm[start + base + lane] : 0;
        int j = 0;
        for (; j + 4 <= rem; j += 4) {
            int e0 = __shfl(eidv, j), e1 = __shfl(eidv, j + 1);
            int e2 = __shfl(eidv, j + 2), e3 = __shfl(eidv, j + 3);
            if (lane < OUT_FEAT / 2) {
                unsigned d0 = mp[(size_t)e0 * (MSG_STRIDE / 2) + lane];
                unsigned d1 = mp[(size_t)e1 * (MSG_STRIDE / 2) + lane];
                unsigned d2 = mp[(size_t)e2 * (MSG_STRIDE / 2) + lane];
                unsigned d3 = mp[(size_t)e3 * (MSG_STRIDE / 2) + lane];
                ax += bf2f(d0 & 0xffffu) + bf2f(d1 & 0xffffu) + bf2f(d2 & 0xffffu) + bf2f(d3 & 0xffffu);
                ay += bf2f(d0 >> 16) + bf2f(d1 >> 16) + bf2f(d2 >> 16) + bf2f(d3 >> 16);
            }
        }
        for (; j < rem; ++j) {
            int e0 = __shfl(eidv, j);
            if (lane < OUT_FEAT / 2) {
                unsigned d0 = mp[(size_t)e0 * (MSG_STRIDE / 2) + lane];
                ax += bf2f(d0 & 0xffffu);
                ay += bf2f(d0 >> 16);
            }
        }
    }
    if (lane < OUT_FEAT / 2) {
        float2* op = reinterpret_cast<float2*>(out + (size_t)n * OUT_FEAT) + lane;
        float2 cur = *op;
        cur.x += ax; cur.y += ay;
        *op = cur;
    }
}

extern "C" void kernel_launch(void* const* d_in, const int* in_sizes, int n_in,
                              void* d_out, int out_size, void* d_ws, size_t ws_size,
                              hipStream_t stream) {
    const float* h      = (const float*)d_in[0];
    const float* efeat  = (const float*)d_in[1];
    const float* norm   = (const float*)d_in[2];
    const float* weight = (const float*)d_in[3];
    const float* attn   = (const float*)d_in[4];
    const float* fc_w   = (const float*)d_in[5];
    const float* loop_w = (const float*)d_in[6];
    const int*   rel    = (const int*)d_in[7];
    const int*   src    = (const int*)d_in[8];
    const int*   dst    = (const int*)d_in[9];
    float* out = (float*)d_out;

    char* ws = (char*)d_ws;
    unsigned short* Bimg = (unsigned short*)(ws + WS_B);
    int* cnt    = (int*)(ws + WS_CNT);
    int* offs   = (int*)(ws + WS_OFFS);
    int* cursor = (int*)(ws + WS_CURSOR);
    int* bsum   = (int*)(ws + WS_BSUM);
    int* perm   = (int*)(ws + WS_PERM);
    unsigned short* msg = (unsigned short*)(ws + WS_MSG);

    build_B<<<(NP * 16 + 255) / 256, 256, 0, stream>>>(fc_w, Bimg);
    loop_kernel<<<N_NODES / 16, 256, 0, stream>>>(h, loop_w, out);

    if (ws_size >= (size_t)WS_NEEDED) {
        hipMemsetAsync(cnt, 0, NNODES_PAD * sizeof(int), stream);
        hist_kernel<<<(N_EDGES + 511) / 512, 512, 0, stream>>>(dst, cnt);
        scan1<<<NNODES_PAD / 1024, 1024, 0, stream>>>(cnt, offs, bsum);
        scan2<<<1, 64, 0, stream>>>(bsum);
        scan3<<<NNODES_PAD / 1024, 1024, 0, stream>>>(offs, bsum, cursor);
        scatter_kernel<<<(N_EDGES + 511) / 512, 512, 0, stream>>>(dst, cursor, perm);
        edge_kernel<false><<<N_EDGES / MB, 512, 0, stream>>>(
            h, efeat, norm, weight, attn, rel, src, dst, Bimg, out, msg);
        gather_kernel<<<(N_NODES + 3) / 4, 256, 0, stream>>>(msg, offs, cnt, perm, out);
    } else {
        edge_kernel<true><<<N_EDGES / MB, 512, 0, stream>>>(
            h, efeat, norm, weight, attn, rel, src, dst, Bimg, out, msg);
    }
}

// Round 3
// 627.175 us; speedup vs baseline: 2.0717x; 2.0717x over previous
//
#include <hip/hip_runtime.h>
#include <hip/hip_bf16.h>

#define N_NODES 50000
#define N_EDGES 800000
#define IN_FEAT 100
#define OUT_FEAT 100
#define NUM_RELS 200
#define NUM_HEADS 3

#define KP 128          // padded K (100 -> 128)
#define NPH 112         // per-head padded N (100 -> 112 = 7*16)
#define NP  336         // 3 * 112
#define MB  128         // edges (or node-rows) per block
#define NT_O 7          // NPH/16

// ---- workspace layout (bytes) ----
#define WS_B       0u           // fc_w^T bf16 image, per-head swizzled: 336*128*2 = 86016
#define WS_LW      86016u       // loop_w^T bf16 image: 112*128*2 = 28672
#define WS_CNT     114688u      // 50176 ints
#define WS_OFFS    315392u
#define WS_CURSOR  516096u
#define WS_BSUM    716800u      // 64 ints
#define WS_PERM    717056u      // 800000 ints
#define WS_NEEDED  3917056u
#define NNODES_PAD 50176        // 49*1024

typedef __attribute__((ext_vector_type(8))) short short8;
typedef __attribute__((ext_vector_type(4))) float f32x4;

__device__ __forceinline__ unsigned short f2bf(float f) {
    unsigned u = __builtin_bit_cast(unsigned, f);
    unsigned r = u + 0x7FFFu + ((u >> 16) & 1u);
    return (unsigned short)(r >> 16);
}
__device__ __forceinline__ float bf2f(unsigned hs) {
    return __builtin_bit_cast(float, hs << 16);
}

// ---------------------------------------------------------------------------
// Build bf16 transposed weight images, per-head-region XOR-swizzled so edge
// blocks copy them LINEARLY into LDS and read fragments with the same swizzle.
// k-storage granule g (=kt*4+g4), elem j2 in [0,8): k = kt*32+(j2>>2)*16+g4*4+(j2&3)
// ---------------------------------------------------------------------------
__global__ __launch_bounds__(256) void build_B(const float* __restrict__ fc_w,
                                               unsigned short* __restrict__ Bws) {
    int idx = blockIdx.x * 256 + threadIdx.x;     // granule id: n*16 + g
    if (idx >= NP * 16) return;
    int n = idx >> 4, g = idx & 15;
    int head = n / NPH, nl = n - head * NPH;      // nl = o within head
    int kt = g >> 2, g4 = g & 3;
    unsigned p[4];
#pragma unroll
    for (int half = 0; half < 2; ++half) {
#pragma unroll
        for (int jp = 0; jp < 2; ++jp) {
            int k_lo = kt * 32 + half * 16 + g4 * 4 + jp * 2;
            int k_hi = k_lo + 1;
            float vlo = (k_lo < IN_FEAT && nl < OUT_FEAT)
                      ? fc_w[k_lo * (OUT_FEAT * NUM_HEADS) + head * OUT_FEAT + nl] : 0.f;
            float vhi = (k_hi < IN_FEAT && nl < OUT_FEAT)
                      ? fc_w[k_hi * (OUT_FEAT * NUM_HEADS) + head * OUT_FEAT + nl] : 0.f;
            p[half * 2 + jp] = (unsigned)f2bf(vlo) | ((unsigned)f2bf(vhi) << 16);
        }
    }
    unsigned off = (unsigned)(head * (NPH * KP * 2)) +
                   (((unsigned)(nl * (KP * 2) + g * 16)) ^ (((unsigned)(nl & 7)) << 4));
    *reinterpret_cast<int4*>(reinterpret_cast<char*>(Bws) + off) =
        make_int4((int)p[0], (int)p[1], (int)p[2], (int)p[3]);
}

__global__ __launch_bounds__(256) void build_LW(const float* __restrict__ loop_w,
                                                unsigned short* __restrict__ LWws) {
    int idx = blockIdx.x * 256 + threadIdx.x;     // granule id: nl*16 + g
    if (idx >= NPH * 16) return;
    int nl = idx >> 4, g = idx & 15;
    int kt = g >> 2, g4 = g & 3;
    unsigned p[4];
#pragma unroll
    for (int half = 0; half < 2; ++half) {
#pragma unroll
        for (int jp = 0; jp < 2; ++jp) {
            int k_lo = kt * 32 + half * 16 + g4 * 4 + jp * 2;
            int k_hi = k_lo + 1;
            float vlo = (k_lo < IN_FEAT && nl < OUT_FEAT) ? loop_w[k_lo * OUT_FEAT + nl] : 0.f;
            float vhi = (k_hi < IN_FEAT && nl < OUT_FEAT) ? loop_w[k_hi * OUT_FEAT + nl] : 0.f;
            p[half * 2 + jp] = (unsigned)f2bf(vlo) | ((unsigned)f2bf(vhi) << 16);
        }
    }
    unsigned off = ((unsigned)(nl * (KP * 2) + g * 16)) ^ (((unsigned)(nl & 7)) << 4);
    *reinterpret_cast<int4*>(reinterpret_cast<char*>(LWws) + off) =
        make_int4((int)p[0], (int)p[1], (int)p[2], (int)p[3]);
}

// ---------------------------------------------------------------------------
// Self-loop GEMM: out = h @ loop_w via bf16 MFMA. Fully (re)writes out.
// ---------------------------------------------------------------------------
__global__ __launch_bounds__(512, 2) void loop_gemm(const float* __restrict__ h,
                                                    const unsigned short* __restrict__ LWimg,
                                                    float* __restrict__ out) {
    __shared__ unsigned short Alds[MB * KP];   // 32768 B
    __shared__ unsigned short Blds[NPH * KP];  // 28672 B
    const int tid = threadIdx.x;
    const int rbase = blockIdx.x * MB;

    {
        const int4* sp = reinterpret_cast<const int4*>(LWimg);
        int4* dp = reinterpret_cast<int4*>(Blds);
        for (int i = tid; i < NPH * KP / 8; i += 512) dp[i] = sp[i];
    }
    for (int gi = tid; gi < MB * 16; gi += 512) {
        int row = gi >> 4, g = gi & 15;
        int grow = rbase + row;
        int kt = g >> 2, g4 = g & 3;
        const float* hrow = h + (size_t)grow * IN_FEAT;
        int k0 = kt * 32 + g4 * 4, k1 = k0 + 16;
        bool ok = grow < N_NODES;
        float4 va = (ok && k0 + 4 <= IN_FEAT) ? *reinterpret_cast<const float4*>(hrow + k0)
                                              : make_float4(0.f, 0.f, 0.f, 0.f);
        float4 vb = (ok && k1 + 4 <= IN_FEAT) ? *reinterpret_cast<const float4*>(hrow + k1)
                                              : make_float4(0.f, 0.f, 0.f, 0.f);
        unsigned p0 = (unsigned)f2bf(va.x) | ((unsigned)f2bf(va.y) << 16);
        unsigned p1 = (unsigned)f2bf(va.z) | ((unsigned)f2bf(va.w) << 16);
        unsigned p2 = (unsigned)f2bf(vb.x) | ((unsigned)f2bf(vb.y) << 16);
        unsigned p3 = (unsigned)f2bf(vb.z) | ((unsigned)f2bf(vb.w) << 16);
        unsigned off = ((unsigned)(row * (KP * 2) + g * 16)) ^ (((unsigned)(row & 7)) << 4);
        *reinterpret_cast<int4*>(reinterpret_cast<char*>(Alds) + off) =
            make_int4((int)p0, (int)p1, (int)p2, (int)p3);
    }
    __syncthreads();

    const int wave = tid >> 6, lane = tid & 63;
    const int lrow = lane & 15, lk = lane >> 4;
    const int arow = wave * 16 + lrow;
    const unsigned aswz = ((unsigned)(arow & 7)) << 4;
    const unsigned bswz = ((unsigned)(lrow & 7)) << 4;

    f32x4 acc[NT_O];
#pragma unroll
    for (int i = 0; i < NT_O; ++i) acc[i] = (f32x4){0.f, 0.f, 0.f, 0.f};

#pragma unroll
    for (int kt = 0; kt < 4; ++kt) {
        unsigned aoff = ((unsigned)(arow * (KP * 2) + kt * 64 + lk * 16)) ^ aswz;
        short8 afrag = *reinterpret_cast<const short8*>(
            reinterpret_cast<const char*>(Alds) + aoff);
#pragma unroll
        for (int nt = 0; nt < NT_O; ++nt) {
            unsigned boff = ((unsigned)((nt * 16 + lrow) * (KP * 2) + kt * 64 + lk * 16)) ^ bswz;
            short8 bfrag = *reinterpret_cast<const short8*>(
                reinterpret_cast<const char*>(Blds) + boff);
            acc[nt] = __builtin_amdgcn_mfma_f32_16x16x32_bf16(afrag, bfrag, acc[nt], 0, 0, 0);
        }
    }
    // C/D layout: col(o) = lane&15, row = (lane>>4)*4 + reg
#pragma unroll
    for (int nt = 0; nt < NT_O; ++nt) {
        int o = nt * 16 + lrow;
        if (o < OUT_FEAT) {
#pragma unroll
            for (int r = 0; r < 4; ++r) {
                int grow = rbase + wave * 16 + lk * 4 + r;
                if (grow < N_NODES) out[(size_t)grow * OUT_FEAT + o] = acc[nt][r];
            }
        }
    }
}

// ---------------------------------------------------------------------------
// CSR construction: histogram -> scan -> scatter (perm = edge ids sorted by dst)
// ---------------------------------------------------------------------------
__global__ __launch_bounds__(512) void hist_kernel(const int* __restrict__ dst,
                                                   int* __restrict__ cnt) {
    int e = blockIdx.x * 512 + threadIdx.x;
    if (e < N_EDGES) atomicAdd(&cnt[dst[e]], 1);
}

__global__ __launch_bounds__(1024) void scan1(const int* __restrict__ cnt,
                                              int* __restrict__ offs,
                                              int* __restrict__ bsum) {
    __shared__ int s[1024];
    int i = blockIdx.x * 1024 + threadIdx.x;
    int v = (i < N_NODES) ? cnt[i] : 0;
    s[threadIdx.x] = v;
    __syncthreads();
    for (int d = 1; d < 1024; d <<= 1) {
        int t = (threadIdx.x >= d) ? s[threadIdx.x - d] : 0;
        __syncthreads();
        s[threadIdx.x] += t;
        __syncthreads();
    }
    offs[i] = s[threadIdx.x] - v;
    if (threadIdx.x == 1023) bsum[blockIdx.x] = s[1023];
}

__global__ __launch_bounds__(64) void scan2(int* __restrict__ bsum) {
    __shared__ int s[64];
    int v = (threadIdx.x < NNODES_PAD / 1024) ? bsum[threadIdx.x] : 0;
    s[threadIdx.x] = v;
    __syncthreads();
    for (int d = 1; d < 64; d <<= 1) {
        int t = (threadIdx.x >= d) ? s[threadIdx.x - d] : 0;
        __syncthreads();
        s[threadIdx.x] += t;
        __syncthreads();
    }
    bsum[threadIdx.x] = s[threadIdx.x] - v;
}

__global__ __launch_bounds__(1024) void scan3(int* __restrict__ offs,
                                              const int* __restrict__ bsum,
                                              int* __restrict__ cursor) {
    int i = blockIdx.x * 1024 + threadIdx.x;
    int v = offs[i] + bsum[blockIdx.x];
    offs[i] = v;
    cursor[i] = v;
}

__global__ __launch_bounds__(512) void scatter_kernel(const int* __restrict__ dst,
                                                      int* __restrict__ cursor,
                                                      int* __restrict__ perm) {
    int e = blockIdx.x * 512 + threadIdx.x;
    if (e < N_EDGES) {
        int p = atomicAdd(&cursor[dst[e]], 1);
        perm[p] = e;
    }
}

// ---------------------------------------------------------------------------
// Fused edge kernel. SORTED: edges come via perm (dst-sorted); messages staged
// bf16 in Alds (reused), then per-wave segmented reduction -> plain RMW for
// block-interior dst runs, atomics only for the <=2 boundary runs.
// !SORTED fallback: identity order + atomicAdd per element.
// B staged per-head (28 KB) so total LDS = 63.5 KB -> 2 blocks/CU.
// ---------------------------------------------------------------------------
template<bool SORTED>
__global__ __launch_bounds__(512, 2) void edge_kernel(
        const float* __restrict__ h, const float* __restrict__ efeat,
        const float* __restrict__ norm, const float* __restrict__ weight,
        const float* __restrict__ attn, const int* __restrict__ rel,
        const int* __restrict__ src, const int* __restrict__ dst,
        const int* __restrict__ perm, const unsigned short* __restrict__ Bimg,
        float* __restrict__ out) {

    __shared__ unsigned short Alds[MB * KP];    // 32768 B; reused for bf16 msgs
    __shared__ unsigned short Blds[NPH * KP];   // 28672 B, one head at a time
    __shared__ int   m_rel[MB];
    __shared__ int   m_src[MB];
    __shared__ int   m_dst[MB];
    __shared__ float m_nrm[MB];

    const int tid = threadIdx.x;
    const int ebase = blockIdx.x * MB;

    if (tid < MB) {
        int eid = SORTED ? perm[ebase + tid] : (ebase + tid);
        int rl = rel[eid]; int sr = src[eid]; int d = dst[eid];
        m_rel[tid] = rl; m_src[tid] = sr; m_dst[tid] = d; m_nrm[tid] = norm[d];
    }
    // ---- stage A: e rows (gathered via perm if SORTED) f32 -> bf16, swizzled ----
    for (int gi = tid; gi < MB * 16; gi += 512) {
        int row = gi >> 4, g = gi & 15;
        int eid = SORTED ? perm[ebase + row] : (ebase + row);
        int kt = g >> 2, g4 = g & 3;
        const float* erow = efeat + (size_t)eid * IN_FEAT;
        int k0 = kt * 32 + g4 * 4, k1 = k0 + 16;
        float4 va = (k0 + 4 <= IN_FEAT) ? *reinterpret_cast<const float4*>(erow + k0)
                                        : make_float4(0.f, 0.f, 0.f, 0.f);
        float4 vb = (k1 + 4 <= IN_FEAT) ? *reinterpret_cast<const float4*>(erow + k1)
                                        : make_float4(0.f, 0.f, 0.f, 0.f);
        unsigned p0 = (unsigned)f2bf(va.x) | ((unsigned)f2bf(va.y) << 16);
        unsigned p1 = (unsigned)f2bf(va.z) | ((unsigned)f2bf(va.w) << 16);
        unsigned p2 = (unsigned)f2bf(vb.x) | ((unsigned)f2bf(vb.y) << 16);
        unsigned p3 = (unsigned)f2bf(vb.z) | ((unsigned)f2bf(vb.w) << 16);
        unsigned off = ((unsigned)(row * (KP * 2) + g * 16)) ^ (((unsigned)(row & 7)) << 4);
        *reinterpret_cast<int4*>(reinterpret_cast<char*>(Alds) + off) =
            make_int4((int)p0, (int)p1, (int)p2, (int)p3);
    }
    __syncthreads();

    const int wave = tid >> 6, lane = tid & 63;
    const int lrow = lane & 15, lk = lane >> 4;
    const int arow = wave * 16 + lrow;
    const unsigned aswz = ((unsigned)(arow & 7)) << 4;
    const unsigned bswz = ((unsigned)(lrow & 7)) << 4;

    int rl_r[4];
#pragma unroll
    for (int r = 0; r < 4; ++r) rl_r[r] = m_rel[wave * 16 + lk * 4 + r];

    float feat[NT_O][4];
#pragma unroll
    for (int nt = 0; nt < NT_O; ++nt)
#pragma unroll
        for (int r = 0; r < 4; ++r) feat[nt][r] = 0.f;

    for (int hh = 0; hh < NUM_HEADS; ++hh) {
        // stage this head's B tile (image is pre-swizzled; linear copy)
        {
            const int4* sp = reinterpret_cast<const int4*>(Bimg) + hh * (NPH * KP / 8);
            int4* dp = reinterpret_cast<int4*>(Blds);
            for (int i = tid; i < NPH * KP / 8; i += 512) dp[i] = sp[i];
        }
        __syncthreads();

        f32x4 acc[NT_O];
#pragma unroll
        for (int i = 0; i < NT_O; ++i) acc[i] = (f32x4){0.f, 0.f, 0.f, 0.f};

#pragma unroll
        for (int kt = 0; kt < 4; ++kt) {
            unsigned aoff = ((unsigned)(arow * (KP * 2) + kt * 64 + lk * 16)) ^ aswz;
            short8 afrag = *reinterpret_cast<const short8*>(
                reinterpret_cast<const char*>(Alds) + aoff);
#pragma unroll
            for (int nt = 0; nt < NT_O; ++nt) {
                unsigned boff = ((unsigned)((nt * 16 + lrow) * (KP * 2) + kt * 64 + lk * 16)) ^ bswz;
                short8 bfrag = *reinterpret_cast<const short8*>(
                    reinterpret_cast<const char*>(Blds) + boff);
                acc[nt] = __builtin_amdgcn_mfma_f32_16x16x32_bf16(afrag, bfrag, acc[nt], 0, 0, 0);
            }
        }
        // fold this head into feat (leaky_relu(attn * fc))
#pragma unroll
        for (int nt = 0; nt < NT_O; ++nt) {
            int o = nt * 16 + lrow;
            if (o < OUT_FEAT) {
#pragma unroll
                for (int r = 0; r < 4; ++r) {
                    float v = acc[nt][r] *
                              attn[rl_r[r] * (NUM_HEADS * OUT_FEAT) + hh * OUT_FEAT + o];
                    feat[nt][r] += (v > 0.f) ? v : 0.2f * v;
                }
            }
        }
        __syncthreads();   // Blds (and final-iter: Alds) reads done before overwrite
    }

    // ---- epilogue: msg = (h[src]*w[rel] + feat) * norm[dst] ----
#pragma unroll
    for (int nt = 0; nt < NT_O; ++nt) {
        int o = nt * 16 + lrow;
        if (o < OUT_FEAT) {
#pragma unroll
            for (int r = 0; r < 4; ++r) {
                int el = wave * 16 + lk * 4 + r;
                int sr = m_src[el];
                float nm = m_nrm[el];
                float mg = h[(size_t)sr * IN_FEAT + o] * weight[rl_r[r] * OUT_FEAT + o];
                float val = (mg + feat[nt][r]) * nm;
                if (SORTED) {
                    Alds[el * KP + o] = f2bf(val);
                } else {
                    atomicAdd(&out[(size_t)m_dst[el] * OUT_FEAT + o], val);
                }
            }
        }
    }

    if (SORTED) {
        __syncthreads();
        // segmented reduction: wave w owns runs whose head lies in rows [w*16, w*16+16)
        const unsigned* Msg = reinterpret_cast<const unsigned*>(Alds);
        const int c = lane;               // uint column (2 floats)
        if (c < OUT_FEAT / 2) {
            int i = wave * 16;
            const int wend = i + 16;
            while (i < wend && !(i == 0 || m_dst[i] != m_dst[i - 1])) ++i;
            while (i < wend) {
                int d = m_dst[i];
                int runstart = i;
                float sx = 0.f, sy = 0.f;
                while (i < MB && m_dst[i] == d) {
                    unsigned u = Msg[i * (KP / 2) + c];
                    sx += bf2f(u & 0xffffu);
                    sy += bf2f(u >> 16);
                    ++i;
                }
                float* op = out + (size_t)d * OUT_FEAT + 2 * c;
                if (runstart == 0 || i == MB) {      // may straddle block boundary
                    atomicAdd(op, sx);
                    atomicAdd(op + 1, sy);
                } else {                              // block-interior: unique owner
                    op[0] += sx;
                    op[1] += sy;
                }
            }
        }
    }
}

extern "C" void kernel_launch(void* const* d_in, const int* in_sizes, int n_in,
                              void* d_out, int out_size, void* d_ws, size_t ws_size,
                              hipStream_t stream) {
    const float* h      = (const float*)d_in[0];
    const float* efeat  = (const float*)d_in[1];
    const float* norm   = (const float*)d_in[2];
    const float* weight = (const float*)d_in[3];
    const float* attn   = (const float*)d_in[4];
    const float* fc_w   = (const float*)d_in[5];
    const float* loop_w = (const float*)d_in[6];
    const int*   rel    = (const int*)d_in[7];
    const int*   src    = (const int*)d_in[8];
    const int*   dst    = (const int*)d_in[9];
    float* out = (float*)d_out;

    char* ws = (char*)d_ws;
    unsigned short* Bimg  = (unsigned short*)(ws + WS_B);
    unsigned short* LWimg = (unsigned short*)(ws + WS_LW);
    int* cnt    = (int*)(ws + WS_CNT);
    int* offs   = (int*)(ws + WS_OFFS);
    int* cursor = (int*)(ws + WS_CURSOR);
    int* bsum   = (int*)(ws + WS_BSUM);
    int* perm   = (int*)(ws + WS_PERM);

    build_B<<<(NP * 16 + 255) / 256, 256, 0, stream>>>(fc_w, Bimg);
    build_LW<<<(NPH * 16 + 255) / 256, 256, 0, stream>>>(loop_w, LWimg);
    // out = h @ loop_w (rewrites every element; edge adds accumulate on top)
    loop_gemm<<<(N_NODES + MB - 1) / MB, 512, 0, stream>>>(h, LWimg, out);

    if (ws_size >= (size_t)WS_NEEDED) {
        hipMemsetAsync(cnt, 0, NNODES_PAD * sizeof(int), stream);
        hist_kernel<<<(N_EDGES + 511) / 512, 512, 0, stream>>>(dst, cnt);
        scan1<<<NNODES_PAD / 1024, 1024, 0, stream>>>(cnt, offs, bsum);
        scan2<<<1, 64, 0, stream>>>(bsum);
        scan3<<<NNODES_PAD / 1024, 1024, 0, stream>>>(offs, bsum, cursor);
        scatter_kernel<<<(N_EDGES + 511) / 512, 512, 0, stream>>>(dst, cursor, perm);
        edge_kernel<true><<<N_EDGES / MB, 512, 0, stream>>>(
            h, efeat, norm, weight, attn, rel, src, dst, perm, Bimg, out);
    } else {
        edge_kernel<false><<<N_EDGES / MB, 512, 0, stream>>>(
            h, efeat, norm, weight, attn, rel, src, dst, nullptr, Bimg, out);
    }
}

// Round 4
// 485.809 us; speedup vs baseline: 2.6745x; 1.2910x over previous
//
#include <hip/hip_runtime.h>
#include <hip/hip_bf16.h>

#define N_NODES 50000
#define N_EDGES 800000
#define IN_FEAT 100
#define OUT_FEAT 100
#define NUM_RELS 200
#define NUM_HEADS 3

#define KP 128          // padded K (100 -> 128)
#define NPH 112         // per-head padded N (100 -> 112 = 7*16)
#define NP  336         // 3 * 112
#define MB  128         // edges (or node-rows) per block
#define NT_O 7          // NPH/16

// ---- workspace layout (bytes) ----
#define WS_B       0u           // fc_w^T bf16 image, per-head swizzled: 86016
#define WS_LW      86016u       // loop_w^T bf16 image: 28672
#define WS_CNT     114688u      // 50176 ints
#define WS_OFFS    315392u
#define WS_CURSOR  516096u
#define WS_BSUM    716800u      // 64 ints
#define WS_PERM    717056u      // 800000 ints
#define WS_FEAT    3917056u     // bf16 feat rows, 112 ushorts (224 B) each
#define NNODES_PAD 50176        // 49*1024

typedef __attribute__((ext_vector_type(8))) short short8;
typedef __attribute__((ext_vector_type(4))) float f32x4;

__device__ __forceinline__ unsigned short f2bf(float f) {
    unsigned u = __builtin_bit_cast(unsigned, f);
    unsigned r = u + 0x7FFFu + ((u >> 16) & 1u);
    return (unsigned short)(r >> 16);
}
__device__ __forceinline__ float bf2f(unsigned hs) {
    return __builtin_bit_cast(float, hs << 16);
}

// ---------------------------------------------------------------------------
// Build bf16 transposed weight images, per-head-region XOR-swizzled.
// k-storage granule g (=kt*4+g4), elem j2 in [0,8): k = kt*32+(j2>>2)*16+g4*4+(j2&3)
// ---------------------------------------------------------------------------
__global__ __launch_bounds__(256) void build_B(const float* __restrict__ fc_w,
                                               unsigned short* __restrict__ Bws) {
    int idx = blockIdx.x * 256 + threadIdx.x;     // granule id: n*16 + g
    if (idx >= NP * 16) return;
    int n = idx >> 4, g = idx & 15;
    int head = n / NPH, nl = n - head * NPH;      // nl = o within head
    int kt = g >> 2, g4 = g & 3;
    unsigned p[4];
#pragma unroll
    for (int half = 0; half < 2; ++half) {
#pragma unroll
        for (int jp = 0; jp < 2; ++jp) {
            int k_lo = kt * 32 + half * 16 + g4 * 4 + jp * 2;
            int k_hi = k_lo + 1;
            float vlo = (k_lo < IN_FEAT && nl < OUT_FEAT)
                      ? fc_w[k_lo * (OUT_FEAT * NUM_HEADS) + head * OUT_FEAT + nl] : 0.f;
            float vhi = (k_hi < IN_FEAT && nl < OUT_FEAT)
                      ? fc_w[k_hi * (OUT_FEAT * NUM_HEADS) + head * OUT_FEAT + nl] : 0.f;
            p[half * 2 + jp] = (unsigned)f2bf(vlo) | ((unsigned)f2bf(vhi) << 16);
        }
    }
    unsigned off = (unsigned)(head * (NPH * KP * 2)) +
                   (((unsigned)(nl * (KP * 2) + g * 16)) ^ (((unsigned)(nl & 7)) << 4));
    *reinterpret_cast<int4*>(reinterpret_cast<char*>(Bws) + off) =
        make_int4((int)p[0], (int)p[1], (int)p[2], (int)p[3]);
}

__global__ __launch_bounds__(256) void build_LW(const float* __restrict__ loop_w,
                                                unsigned short* __restrict__ LWws) {
    int idx = blockIdx.x * 256 + threadIdx.x;
    if (idx >= NPH * 16) return;
    int nl = idx >> 4, g = idx & 15;
    int kt = g >> 2, g4 = g & 3;
    unsigned p[4];
#pragma unroll
    for (int half = 0; half < 2; ++half) {
#pragma unroll
        for (int jp = 0; jp < 2; ++jp) {
            int k_lo = kt * 32 + half * 16 + g4 * 4 + jp * 2;
            int k_hi = k_lo + 1;
            float vlo = (k_lo < IN_FEAT && nl < OUT_FEAT) ? loop_w[k_lo * OUT_FEAT + nl] : 0.f;
            float vhi = (k_hi < IN_FEAT && nl < OUT_FEAT) ? loop_w[k_hi * OUT_FEAT + nl] : 0.f;
            p[half * 2 + jp] = (unsigned)f2bf(vlo) | ((unsigned)f2bf(vhi) << 16);
        }
    }
    unsigned off = ((unsigned)(nl * (KP * 2) + g * 16)) ^ (((unsigned)(nl & 7)) << 4);
    *reinterpret_cast<int4*>(reinterpret_cast<char*>(LWws) + off) =
        make_int4((int)p[0], (int)p[1], (int)p[2], (int)p[3]);
}

// ---------------------------------------------------------------------------
// Self-loop GEMM: out = h @ loop_w via bf16 MFMA. Fully (re)writes out.
// ---------------------------------------------------------------------------
__global__ __launch_bounds__(512, 2) void loop_gemm(const float* __restrict__ h,
                                                    const unsigned short* __restrict__ LWimg,
                                                    float* __restrict__ out) {
    __shared__ unsigned short Alds[MB * KP];   // 32768 B
    __shared__ unsigned short Blds[NPH * KP];  // 28672 B
    const int tid = threadIdx.x;
    const int rbase = blockIdx.x * MB;

    {
        const int4* sp = reinterpret_cast<const int4*>(LWimg);
        int4* dp = reinterpret_cast<int4*>(Blds);
        for (int i = tid; i < NPH * KP / 8; i += 512) dp[i] = sp[i];
    }
    for (int gi = tid; gi < MB * 16; gi += 512) {
        int row = gi >> 4, g = gi & 15;
        int grow = rbase + row;
        int kt = g >> 2, g4 = g & 3;
        const float* hrow = h + (size_t)grow * IN_FEAT;
        int k0 = kt * 32 + g4 * 4, k1 = k0 + 16;
        bool ok = grow < N_NODES;
        float4 va = (ok && k0 + 4 <= IN_FEAT) ? *reinterpret_cast<const float4*>(hrow + k0)
                                              : make_float4(0.f, 0.f, 0.f, 0.f);
        float4 vb = (ok && k1 + 4 <= IN_FEAT) ? *reinterpret_cast<const float4*>(hrow + k1)
                                              : make_float4(0.f, 0.f, 0.f, 0.f);
        unsigned p0 = (unsigned)f2bf(va.x) | ((unsigned)f2bf(va.y) << 16);
        unsigned p1 = (unsigned)f2bf(va.z) | ((unsigned)f2bf(va.w) << 16);
        unsigned p2 = (unsigned)f2bf(vb.x) | ((unsigned)f2bf(vb.y) << 16);
        unsigned p3 = (unsigned)f2bf(vb.z) | ((unsigned)f2bf(vb.w) << 16);
        unsigned off = ((unsigned)(row * (KP * 2) + g * 16)) ^ (((unsigned)(row & 7)) << 4);
        *reinterpret_cast<int4*>(reinterpret_cast<char*>(Alds) + off) =
            make_int4((int)p0, (int)p1, (int)p2, (int)p3);
    }
    __syncthreads();

    const int wave = tid >> 6, lane = tid & 63;
    const int lrow = lane & 15, lk = lane >> 4;
    const int arow = wave * 16 + lrow;
    const unsigned aswz = ((unsigned)(arow & 7)) << 4;
    const unsigned bswz = ((unsigned)(lrow & 7)) << 4;

    f32x4 acc[NT_O];
#pragma unroll
    for (int i = 0; i < NT_O; ++i) acc[i] = (f32x4){0.f, 0.f, 0.f, 0.f};

#pragma unroll
    for (int kt = 0; kt < 4; ++kt) {
        unsigned aoff = ((unsigned)(arow * (KP * 2) + kt * 64 + lk * 16)) ^ aswz;
        short8 afrag = *reinterpret_cast<const short8*>(
            reinterpret_cast<const char*>(Alds) + aoff);
#pragma unroll
        for (int nt = 0; nt < NT_O; ++nt) {
            unsigned boff = ((unsigned)((nt * 16 + lrow) * (KP * 2) + kt * 64 + lk * 16)) ^ bswz;
            short8 bfrag = *reinterpret_cast<const short8*>(
                reinterpret_cast<const char*>(Blds) + boff);
            acc[nt] = __builtin_amdgcn_mfma_f32_16x16x32_bf16(afrag, bfrag, acc[nt], 0, 0, 0);
        }
    }
#pragma unroll
    for (int nt = 0; nt < NT_O; ++nt) {
        int o = nt * 16 + lrow;
        if (o < OUT_FEAT) {
#pragma unroll
            for (int r = 0; r < 4; ++r) {
                int grow = rbase + wave * 16 + lk * 4 + r;
                if (grow < N_NODES) out[(size_t)grow * OUT_FEAT + o] = acc[nt][r];
            }
        }
    }
}

// ---------------------------------------------------------------------------
// CSR construction
// ---------------------------------------------------------------------------
__global__ __launch_bounds__(512) void hist_kernel(const int* __restrict__ dst,
                                                   int* __restrict__ cnt) {
    int e = blockIdx.x * 512 + threadIdx.x;
    if (e < N_EDGES) atomicAdd(&cnt[dst[e]], 1);
}

__global__ __launch_bounds__(1024) void scan1(const int* __restrict__ cnt,
                                              int* __restrict__ offs,
                                              int* __restrict__ bsum) {
    __shared__ int s[1024];
    int i = blockIdx.x * 1024 + threadIdx.x;
    int v = (i < N_NODES) ? cnt[i] : 0;
    s[threadIdx.x] = v;
    __syncthreads();
    for (int d = 1; d < 1024; d <<= 1) {
        int t = (threadIdx.x >= d) ? s[threadIdx.x - d] : 0;
        __syncthreads();
        s[threadIdx.x] += t;
        __syncthreads();
    }
    offs[i] = s[threadIdx.x] - v;
    if (threadIdx.x == 1023) bsum[blockIdx.x] = s[1023];
}

__global__ __launch_bounds__(64) void scan2(int* __restrict__ bsum) {
    __shared__ int s[64];
    int v = (threadIdx.x < NNODES_PAD / 1024) ? bsum[threadIdx.x] : 0;
    s[threadIdx.x] = v;
    __syncthreads();
    for (int d = 1; d < 64; d <<= 1) {
        int t = (threadIdx.x >= d) ? s[threadIdx.x - d] : 0;
        __syncthreads();
        s[threadIdx.x] += t;
        __syncthreads();
    }
    bsum[threadIdx.x] = s[threadIdx.x] - v;
}

__global__ __launch_bounds__(1024) void scan3(int* __restrict__ offs,
                                              const int* __restrict__ bsum,
                                              int* __restrict__ cursor) {
    int i = blockIdx.x * 1024 + threadIdx.x;
    int v = offs[i] + bsum[blockIdx.x];
    offs[i] = v;
    cursor[i] = v;
}

__global__ __launch_bounds__(512) void scatter_kernel(const int* __restrict__ dst,
                                                      int* __restrict__ cursor,
                                                      int* __restrict__ perm) {
    int e = blockIdx.x * 512 + threadIdx.x;
    if (e < N_EDGES) {
        int p = atomicAdd(&cursor[dst[e]], 1);
        perm[p] = e;
    }
}

// ---------------------------------------------------------------------------
// feat kernel: natural edge order, streaming. A-fragments live in registers
// (loaded once, reused across all 3 heads); only per-head B tile in LDS
// (29 KB total). TOWS: write bf16 feat rows to ws. !TOWS fallback: full fused
// epilogue with atomics.
// ---------------------------------------------------------------------------
template<bool TOWS>
__global__ __launch_bounds__(512, 2) void feat_kernel(
        const float* __restrict__ efeat, const int* __restrict__ rel,
        const unsigned short* __restrict__ Bimg, const float* __restrict__ attn,
        const float* __restrict__ h, const float* __restrict__ weight,
        const float* __restrict__ norm, const int* __restrict__ src,
        const int* __restrict__ dst, float* __restrict__ out,
        unsigned short* __restrict__ featws, int lo) {

    __shared__ unsigned short Blds[NPH * KP];   // 28672 B; reused for msg staging
    __shared__ int   m_rel[MB];
    __shared__ int   m_src[MB];
    __shared__ int   m_dst[MB];
    __shared__ float m_nrm[MB];

    const int tid = threadIdx.x;
    const int ebase = lo + blockIdx.x * MB;

    if (tid < MB) {
        int ei = ebase + tid;
        m_rel[tid] = rel[ei];
        if (!TOWS) {
            int d = dst[ei];
            m_src[tid] = src[ei]; m_dst[tid] = d; m_nrm[tid] = norm[d];
        }
    }

    const int wave = tid >> 6, lane = tid & 63;
    const int lrow = lane & 15, lk = lane >> 4;
    const int arow = ebase + wave * 16 + lrow;
    const float* ap = efeat + (size_t)arow * IN_FEAT;

    // ---- A fragments straight from global into registers (coalesced rows) ----
    short8 afrag[4];
#pragma unroll
    for (int kt = 0; kt < 4; ++kt) {
        int k0 = kt * 32 + lk * 4;
        int k1 = k0 + 16;
        float4 va = (k0 + 4 <= IN_FEAT) ? *reinterpret_cast<const float4*>(ap + k0)
                                        : make_float4(0.f, 0.f, 0.f, 0.f);
        float4 vb = (k1 + 4 <= IN_FEAT) ? *reinterpret_cast<const float4*>(ap + k1)
                                        : make_float4(0.f, 0.f, 0.f, 0.f);
        afrag[kt][0] = (short)f2bf(va.x); afrag[kt][1] = (short)f2bf(va.y);
        afrag[kt][2] = (short)f2bf(va.z); afrag[kt][3] = (short)f2bf(va.w);
        afrag[kt][4] = (short)f2bf(vb.x); afrag[kt][5] = (short)f2bf(vb.y);
        afrag[kt][6] = (short)f2bf(vb.z); afrag[kt][7] = (short)f2bf(vb.w);
    }

    const unsigned bswz = ((unsigned)(lrow & 7)) << 4;
    float feat[NT_O][4];
#pragma unroll
    for (int nt = 0; nt < NT_O; ++nt)
#pragma unroll
        for (int r = 0; r < 4; ++r) feat[nt][r] = 0.f;

    int rl_r[4];

    for (int hh = 0; hh < NUM_HEADS; ++hh) {
        {
            const int4* sp = reinterpret_cast<const int4*>(Bimg) + hh * (NPH * KP / 8);
            int4* dp = reinterpret_cast<int4*>(Blds);
            for (int i = tid; i < NPH * KP / 8; i += 512) dp[i] = sp[i];
        }
        __syncthreads();
        if (hh == 0) {
#pragma unroll
            for (int r = 0; r < 4; ++r) rl_r[r] = m_rel[wave * 16 + lk * 4 + r];
        }

        f32x4 acc[NT_O];
#pragma unroll
        for (int i = 0; i < NT_O; ++i) acc[i] = (f32x4){0.f, 0.f, 0.f, 0.f};

#pragma unroll
        for (int kt = 0; kt < 4; ++kt) {
#pragma unroll
            for (int nt = 0; nt < NT_O; ++nt) {
                unsigned boff = ((unsigned)((nt * 16 + lrow) * (KP * 2) + kt * 64 + lk * 16)) ^ bswz;
                short8 bfrag = *reinterpret_cast<const short8*>(
                    reinterpret_cast<const char*>(Blds) + boff);
                acc[nt] = __builtin_amdgcn_mfma_f32_16x16x32_bf16(afrag[kt], bfrag, acc[nt], 0, 0, 0);
            }
        }
        // fold this head: feat += leaky_relu(attn * fc)
#pragma unroll
        for (int nt = 0; nt < NT_O; ++nt) {
            int o = nt * 16 + lrow;
            if (o < OUT_FEAT) {
#pragma unroll
                for (int r = 0; r < 4; ++r) {
                    float v = acc[nt][r] *
                              attn[rl_r[r] * (NUM_HEADS * OUT_FEAT) + hh * OUT_FEAT + o];
                    feat[nt][r] += (v > 0.f) ? v : 0.2f * v;
                }
            }
        }
        __syncthreads();   // Blds reads done before next head's copy / msg staging
    }

    if (TOWS) {
        // stage bf16 feat rows into Blds (128 x 112 ushorts == Blds size), coalesced out
#pragma unroll
        for (int nt = 0; nt < NT_O; ++nt) {
            int o = nt * 16 + lrow;
            if (o < OUT_FEAT) {
#pragma unroll
                for (int r = 0; r < 4; ++r) {
                    int el = wave * 16 + lk * 4 + r;
                    Blds[el * NPH + o] = f2bf(feat[nt][r]);
                }
            }
        }
        __syncthreads();
        int4* gp = reinterpret_cast<int4*>(featws + (size_t)(ebase - lo) * NPH);
        const int4* sp = reinterpret_cast<const int4*>(Blds);
        for (int i = tid; i < MB * NPH / 8; i += 512) gp[i] = sp[i];
    } else {
#pragma unroll
        for (int nt = 0; nt < NT_O; ++nt) {
            int o = nt * 16 + lrow;
            if (o < OUT_FEAT) {
#pragma unroll
                for (int r = 0; r < 4; ++r) {
                    int el = wave * 16 + lk * 4 + r;
                    float mg = h[(size_t)m_src[el] * IN_FEAT + o] * weight[rl_r[r] * OUT_FEAT + o];
                    atomicAdd(&out[(size_t)m_dst[el] * OUT_FEAT + o],
                              (mg + feat[nt][r]) * m_nrm[el]);
                }
            }
        }
    }
}

// ---------------------------------------------------------------------------
// agg kernel: one wave per node. Per edge: feat row (bf16) + h[src] (x) w[rel]
// in f32, accumulate; out += agg * norm. No atomics, no LDS -> max TLP.
// ---------------------------------------------------------------------------
__global__ __launch_bounds__(256, 4) void agg_kernel(
        const unsigned short* __restrict__ featws, const int* __restrict__ offs,
        const int* __restrict__ cnt, const int* __restrict__ perm,
        const int* __restrict__ src, const int* __restrict__ rel,
        const float* __restrict__ h, const float* __restrict__ weight,
        const float* __restrict__ norm, float* __restrict__ out,
        int lo, int hi) {
    int wv = threadIdx.x >> 6, lane = threadIdx.x & 63;
    int n = blockIdx.x * 4 + wv;
    if (n >= N_NODES) return;
    int start = offs[n], deg = cnt[n];
    const int c = lane;                 // uint column: outputs 2c, 2c+1
    float ax = 0.f, ay = 0.f;
    const unsigned* fp = reinterpret_cast<const unsigned*>(featws);

    for (int base = 0; base < deg; base += 64) {
        int rem = deg - base; if (rem > 64) rem = 64;
        int ev = 0, sv = 0, rv = 0;
        if (lane < rem) {
            ev = perm[start + base + lane];
            sv = src[ev];
            rv = rel[ev];
        }
#pragma unroll 1
        for (int j = 0; j < rem; ++j) {
            int e = __shfl(ev, j);
            if (e < lo || e >= hi) continue;          // wave-uniform
            int s = __shfl(sv, j);
            int rl = __shfl(rv, j);
            if (c < OUT_FEAT / 2) {
                float2 h2 = *reinterpret_cast<const float2*>(h + (size_t)s * IN_FEAT + 2 * c);
                float2 w2 = *reinterpret_cast<const float2*>(weight + (size_t)rl * OUT_FEAT + 2 * c);
                unsigned fu = fp[(size_t)(e - lo) * (NPH / 2) + c];
                ax += h2.x * w2.x + bf2f(fu & 0xffffu);
                ay += h2.y * w2.y + bf2f(fu >> 16);
            }
        }
    }
    if (c < OUT_FEAT / 2 && deg > 0) {
        float nm = norm[n];
        float2* op = reinterpret_cast<float2*>(out + (size_t)n * OUT_FEAT) + c;
        float2 cur = *op;
        cur.x += ax * nm; cur.y += ay * nm;
        *op = cur;
    }
}

extern "C" void kernel_launch(void* const* d_in, const int* in_sizes, int n_in,
                              void* d_out, int out_size, void* d_ws, size_t ws_size,
                              hipStream_t stream) {
    const float* h      = (const float*)d_in[0];
    const float* efeat  = (const float*)d_in[1];
    const float* norm   = (const float*)d_in[2];
    const float* weight = (const float*)d_in[3];
    const float* attn   = (const float*)d_in[4];
    const float* fc_w   = (const float*)d_in[5];
    const float* loop_w = (const float*)d_in[6];
    const int*   rel    = (const int*)d_in[7];
    const int*   src    = (const int*)d_in[8];
    const int*   dst    = (const int*)d_in[9];
    float* out = (float*)d_out;

    char* ws = (char*)d_ws;
    unsigned short* Bimg  = (unsigned short*)(ws + WS_B);
    unsigned short* LWimg = (unsigned short*)(ws + WS_LW);
    int* cnt    = (int*)(ws + WS_CNT);
    int* offs   = (int*)(ws + WS_OFFS);
    int* cursor = (int*)(ws + WS_CURSOR);
    int* bsum   = (int*)(ws + WS_BSUM);
    int* perm   = (int*)(ws + WS_PERM);
    unsigned short* featws = (unsigned short*)(ws + WS_FEAT);

    build_B<<<(NP * 16 + 255) / 256, 256, 0, stream>>>(fc_w, Bimg);
    build_LW<<<(NPH * 16 + 255) / 256, 256, 0, stream>>>(loop_w, LWimg);
    loop_gemm<<<(N_NODES + MB - 1) / MB, 512, 0, stream>>>(h, LWimg, out);

    // how many feat rows fit in the remaining workspace?
    long long avail = (long long)ws_size - (long long)WS_FEAT;
    long long rows = (avail > 0) ? avail / (NPH * 2) : 0;
    rows = (rows / MB) * MB;
    if (rows > N_EDGES) rows = N_EDGES;

    if (rows >= 100000) {            // <= 8 passes
        hipMemsetAsync(cnt, 0, NNODES_PAD * sizeof(int), stream);
        hist_kernel<<<(N_EDGES + 511) / 512, 512, 0, stream>>>(dst, cnt);
        scan1<<<NNODES_PAD / 1024, 1024, 0, stream>>>(cnt, offs, bsum);
        scan2<<<1, 64, 0, stream>>>(bsum);
        scan3<<<NNODES_PAD / 1024, 1024, 0, stream>>>(offs, bsum, cursor);
        scatter_kernel<<<(N_EDGES + 511) / 512, 512, 0, stream>>>(dst, cursor, perm);

        for (long long lo = 0; lo < N_EDGES; lo += rows) {
            long long hi = lo + rows; if (hi > N_EDGES) hi = N_EDGES;
            int nb = (int)((hi - lo) / MB);
            feat_kernel<true><<<nb, 512, 0, stream>>>(
                efeat, rel, Bimg, attn, h, weight, norm, src, dst, out,
                featws, (int)lo);
            agg_kernel<<<(N_NODES + 3) / 4, 256, 0, stream>>>(
                featws, offs, cnt, perm, src, rel, h, weight, norm, out,
                (int)lo, (int)hi);
        }
    } else {
        feat_kernel<false><<<N_EDGES / MB, 512, 0, stream>>>(
            efeat, rel, Bimg, attn, h, weight, norm, src, dst, out,
            featws, 0);
    }
}